// Round 1
// baseline (120.605 us; speedup 1.0000x reference)
//
#include <hip/hip_runtime.h>
#include <hip/hip_bf16.h>

#define IN_F 4096
#define OUT_F 11008
#define M_ROWS 64
#define N_GROUPS 32
#define KSPLIT 4
#define GROUPS_PER_BLOCK (N_GROUPS / KSPLIT)   // 8
#define NTILE 64
#define NBLOCKS (OUT_F / NTILE)                // 172
#define QZ_WORDS (OUT_F / 8)                   // 1376

typedef __attribute__((ext_vector_type(8))) short short8;   // bf16x8 fragment (4 VGPRs)
typedef __attribute__((ext_vector_type(4))) float float4v;  // fp32x4 accumulator

// round-to-nearest-even fp32 -> bf16 bits
__device__ __forceinline__ short f2bf(float f) {
    union { float f; unsigned u; } a;
    a.f = f;
    unsigned r = a.u + 0x7FFFu + ((a.u >> 16) & 1u);
    return (short)(r >> 16);
}

// LDS A-chunk layout: 16 u-rows (u = kk*4 + q, covers k0+u*8 .. k0+u*8+7),
// each row 64 m-chunks of 8 bf16 (16B), +1 chunk pad per row to break bank aliasing.
#define LDS_ROW 65

__global__ __launch_bounds__(256) void qlin_kernel(
    const float* __restrict__ x,        // [64, 4096]
    const int*   __restrict__ qweight,  // [512, 11008]
    const int*   __restrict__ qzeros,   // [32, 1376]
    const float* __restrict__ scales,   // [32, 11008]
    const float* __restrict__ bias,     // [11008]
    float* __restrict__ out)            // [64, 11008] (pre-zeroed; atomic accumulate)
{
    __shared__ short lds_a[16 * LDS_ROW * 8];   // 16640 B

    const int blk  = blockIdx.x;
    const int nb   = blk % NBLOCKS;
    const int kg   = blk / NBLOCKS;
    const int n0   = nb * NTILE;
    const int t    = threadIdx.x;
    const int wave = t >> 6;
    const int lane = t & 63;
    const int q    = lane >> 4;       // 0..3 : k-quad
    const int nl   = lane & 15;       // 0..15: n within strip / m within tile
    const int n    = n0 + wave * 16 + nl;

    float4v acc[4];
#pragma unroll
    for (int i = 0; i < 4; ++i) acc[i] = (float4v){0.f, 0.f, 0.f, 0.f};

    // staging assignment: thread t handles m = t>>2, u = (t&3)*4 + i
    const int sm = t >> 2;
    const int su = (t & 3) * 4;

    for (int gi = 0; gi < GROUPS_PER_BLOCK; ++gi) {
        const int g  = kg * GROUPS_PER_BLOCK + gi;
        const int k0 = g * 128;

        __syncthreads();   // previous iteration's LDS reads done before overwrite
#pragma unroll
        for (int i = 0; i < 4; ++i) {
            const int u = su + i;
            const float* src = x + sm * IN_F + k0 + u * 8;
            float4v f0 = *(const float4v*)(src);
            float4v f1 = *(const float4v*)(src + 4);
            short8 h;
            h[0] = f2bf(f0[0]); h[1] = f2bf(f0[1]); h[2] = f2bf(f0[2]); h[3] = f2bf(f0[3]);
            h[4] = f2bf(f1[0]); h[5] = f2bf(f1[1]); h[6] = f2bf(f1[2]); h[7] = f2bf(f1[3]);
            *(short8*)(&lds_a[(u * LDS_ROW + sm) * 8]) = h;
        }
        __syncthreads();

        // per-lane group constants (n fixed per lane)
        const int zword = qzeros[g * QZ_WORDS + (n >> 3)];
        const int z     = ((zword >> ((n & 7) * 4)) & 15) + 1;
        const float s   = scales[g * OUT_F + n];
        const float nz  = -s * (float)z;   // B value = s*nib + nz = s*(nib - z)

#pragma unroll
        for (int kk = 0; kk < 4; ++kk) {
            // one int32 = the 8 k-nibbles this lane needs for its B fragment
            const int row = g * 16 + kk * 4 + q;
            const int qw  = qweight[row * OUT_F + n];
            short8 bfrag;
#pragma unroll
            for (int j = 0; j < 8; ++j) {
                const int nib = (qw >> (4 * j)) & 15;
                bfrag[j] = f2bf(fmaf(s, (float)nib, nz));
            }
            const int u = kk * 4 + q;
#pragma unroll
            for (int mt = 0; mt < 4; ++mt) {
                short8 afrag = *(const short8*)(&lds_a[(u * LDS_ROW + mt * 16 + nl) * 8]);
                acc[mt] = __builtin_amdgcn_mfma_f32_16x16x32_bf16(afrag, bfrag, acc[mt], 0, 0, 0);
            }
        }
    }

    // epilogue: C/D layout col = lane&15 (n), row = q*4 + reg (within 16-row tile)
    const float bv = (kg == 0) ? bias[n] : 0.f;
#pragma unroll
    for (int mt = 0; mt < 4; ++mt) {
#pragma unroll
        for (int r = 0; r < 4; ++r) {
            const int m = mt * 16 + q * 4 + r;
            atomicAdd(&out[m * OUT_F + n], acc[mt][r] + bv);
        }
    }
}

extern "C" void kernel_launch(void* const* d_in, const int* in_sizes, int n_in,
                              void* d_out, int out_size, void* d_ws, size_t ws_size,
                              hipStream_t stream) {
    const float* x       = (const float*)d_in[0];
    const int*   qweight = (const int*)d_in[1];
    const int*   qzeros  = (const int*)d_in[2];
    const float* scales  = (const float*)d_in[3];
    // d_in[4] = g_idx (structure is k/128; unused)
    const float* bias    = (const float*)d_in[5];
    float* out = (float*)d_out;

    hipMemsetAsync(out, 0, (size_t)M_ROWS * OUT_F * sizeof(float), stream);
    qlin_kernel<<<dim3(NBLOCKS * KSPLIT), dim3(256), 0, stream>>>(
        x, qweight, qzeros, scales, bias, out);
}

// Round 3
// 110.175 us; speedup vs baseline: 1.0947x; 1.0947x over previous
//
#include <hip/hip_runtime.h>

#define IN_F 4096
#define OUT_F 11008
#define M_ROWS 64
#define KSPLIT 4
#define GPB 8                     // groups per block = 32/KSPLIT
#define NT_BLK 64                 // n-cols per block (2 waves x 2 strips x 16)
#define NBLK_N (OUT_F / NT_BLK)   // 172
#define QZ_WORDS (OUT_F / 8)      // 1376
#define LDS_ROW 65                // 64 m-chunks + 1 pad

typedef __attribute__((ext_vector_type(8))) short short8;
typedef __attribute__((ext_vector_type(4))) float float4v;

// RNE fp32 -> bf16 (proven in R1)
__device__ __forceinline__ short f2bf(float f) {
    unsigned u = __builtin_bit_cast(unsigned, f);
    return (short)((u + 0x7FFFu + ((u >> 16) & 1u)) >> 16);
}
// truncating fp32 -> bf16 (B-side only; error bound ~0.02 on output)
__device__ __forceinline__ short f2bf_t(float f) {
    return (short)(__builtin_bit_cast(unsigned, f) >> 16);
}

__global__ __launch_bounds__(128) void qlin_kernel(
    const float* __restrict__ x,        // [64, 4096]
    const int*   __restrict__ qweight,  // [512, 11008]
    const int*   __restrict__ qzeros,   // [32, 1376]
    const float* __restrict__ scales,   // [32, 11008]
    const float* __restrict__ bias,     // [11008]
    float* __restrict__ out)            // [64, 11008] pre-zeroed
{
    __shared__ short lds_a[16 * LDS_ROW * 8];   // 16.6 KB: x-tile 64m x 128k bf16

    const int blk  = blockIdx.x;
    const int nb   = blk % NBLK_N;
    const int kg   = blk / NBLK_N;
    const int t    = threadIdx.x;
    const int wave = t >> 6;
    const int lane = t & 63;
    const int q    = lane >> 4;      // k-quad
    const int nl   = lane & 15;
    const int n0   = nb * NT_BLK + wave * 32 + nl;
    const int n1   = n0 + 16;
    const int shz  = (n0 & 7) * 4;   // same for n1

    // staging: thread -> (m = lane, u-block = wave*8). Write instr = 64
    // consecutive 16B chunks -> conflict-free ds_write_b128.
    const int sm   = lane;
    const int ublk = wave * 8;
    const int g0   = kg * GPB;

    float4v xr[16];   // prefetch: 64 floats = k-offsets ublk*8 .. ublk*8+63
    {
        const float* src = x + sm * IN_F + g0 * 128 + ublk * 8;
#pragma unroll
        for (int i = 0; i < 16; ++i) xr[i] = *(const float4v*)(src + i * 4);
    }

    float4v acc0[4], acc1[4];
#pragma unroll
    for (int i = 0; i < 4; ++i) {
        acc0[i] = (float4v){0.f, 0.f, 0.f, 0.f};
        acc1[i] = (float4v){0.f, 0.f, 0.f, 0.f};
    }

#pragma unroll
    for (int gi = 0; gi < GPB; ++gi) {
        const int g = g0 + gi;

        __syncthreads();   // previous iteration's LDS reads complete
#pragma unroll
        for (int i = 0; i < 8; ++i) {
            short8 h;
#pragma unroll
            for (int j = 0; j < 4; ++j) {
                h[j]     = f2bf(xr[2 * i][j]);
                h[j + 4] = f2bf(xr[2 * i + 1][j]);
            }
            *(short8*)&lds_a[((ublk + i) * LDS_ROW + sm) * 8] = h;
        }
        __syncthreads();   // tile ready

        // prefetch next group's x into registers (overlaps compute below)
        if (gi + 1 < GPB) {
            const float* src = x + sm * IN_F + (g + 1) * 128 + ublk * 8;
#pragma unroll
            for (int i = 0; i < 16; ++i) xr[i] = *(const float4v*)(src + i * 4);
        }

        // independent qweight loads up front
        int qwA[4], qwB[4];
#pragma unroll
        for (int kk = 0; kk < 4; ++kk) {
            const int row = g * 16 + kk * 4 + q;
            qwA[kk] = qweight[row * OUT_F + n0];
            qwB[kk] = qweight[row * OUT_F + n1];
        }
        const int   z0 = ((qzeros[g * QZ_WORDS + (n0 >> 3)] >> shz) & 15) + 1;
        const int   z1 = ((qzeros[g * QZ_WORDS + (n1 >> 3)] >> shz) & 15) + 1;
        const float s0 = scales[g * OUT_F + n0];
        const float s1 = scales[g * OUT_F + n1];
        const float nz0 = -s0 * (float)z0;
        const float nz1 = -s1 * (float)z1;

#pragma unroll
        for (int kk = 0; kk < 4; ++kk) {
            short8 b0, b1;
#pragma unroll
            for (int j = 0; j < 8; ++j) {
                b0[j] = f2bf_t(fmaf(s0, (float)((qwA[kk] >> (4 * j)) & 15), nz0));
                b1[j] = f2bf_t(fmaf(s1, (float)((qwB[kk] >> (4 * j)) & 15), nz1));
            }
            const int u = kk * 4 + q;
#pragma unroll
            for (int mt = 0; mt < 4; ++mt) {
                short8 a = *(const short8*)&lds_a[(u * LDS_ROW + mt * 16 + nl) * 8];
                acc0[mt] = __builtin_amdgcn_mfma_f32_16x16x32_bf16(a, b0, acc0[mt], 0, 0, 0);
                acc1[mt] = __builtin_amdgcn_mfma_f32_16x16x32_bf16(a, b1, acc1[mt], 0, 0, 0);
            }
        }
    }

    // epilogue: C/D layout col = lane&15, row = q*4 + reg (proven in R1)
    const float bv0 = (kg == 0) ? bias[n0] : 0.f;
    const float bv1 = (kg == 0) ? bias[n1] : 0.f;
#pragma unroll
    for (int mt = 0; mt < 4; ++mt) {
#pragma unroll
        for (int r = 0; r < 4; ++r) {
            const int m = mt * 16 + q * 4 + r;
            atomicAdd(&out[m * OUT_F + n0], acc0[mt][r] + bv0);
            atomicAdd(&out[m * OUT_F + n1], acc1[mt][r] + bv1);
        }
    }
}

extern "C" void kernel_launch(void* const* d_in, const int* in_sizes, int n_in,
                              void* d_out, int out_size, void* d_ws, size_t ws_size,
                              hipStream_t stream) {
    const float* x       = (const float*)d_in[0];
    const int*   qweight = (const int*)d_in[1];
    const int*   qzeros  = (const int*)d_in[2];
    const float* scales  = (const float*)d_in[3];
    // d_in[4] = g_idx (structurally k/128; unused)
    const float* bias    = (const float*)d_in[5];
    float* out = (float*)d_out;

    hipMemsetAsync(out, 0, (size_t)M_ROWS * OUT_F * sizeof(float), stream);
    qlin_kernel<<<dim3(NBLK_N * KSPLIT), dim3(128), 0, stream>>>(
        x, qweight, qzeros, scales, bias, out);
}

// Round 4
// 102.446 us; speedup vs baseline: 1.1772x; 1.0754x over previous
//
#include <hip/hip_runtime.h>

#define IN_F 4096
#define OUT_F 11008
#define M_ROWS 64
#define KSPLIT 8
#define GPB 4                       // k-groups per block (32/KSPLIT)
#define NT_BLK 128                  // n-cols per block: 4 waves x 2 strips x 16
#define NBLK_N (OUT_F / NT_BLK)     // 86
#define QZ_WORDS (OUT_F / 8)        // 1376

typedef __attribute__((ext_vector_type(8))) short short8;
typedef __attribute__((ext_vector_type(4))) float float4v;

// RNE fp32 -> bf16 (A-side, proven R1/R3)
__device__ __forceinline__ short f2bf(float f) {
    unsigned u = __builtin_bit_cast(unsigned, f);
    return (short)((u + 0x7FFFu + ((u >> 16) & 1u)) >> 16);
}
// truncating fp32 -> bf16 (B-side, proven R3: absmax identical to RNE)
__device__ __forceinline__ short f2bf_t(float f) {
    return (short)(__builtin_bit_cast(unsigned, f) >> 16);
}

// ---- pass 1: x [64,4096] fp32 -> xbf2 [512][64][8] bf16 (k-octet-major) ----
// chunk T = u*64 + m holds bf16(x[m][u*8 .. u*8+7])
__global__ __launch_bounds__(256) void cvt_kernel(const float* __restrict__ x,
                                                  short* __restrict__ xbf2) {
    const int T = blockIdx.x * 256 + threadIdx.x;
    const int u = T >> 6, m = T & 63;
    const float* src = x + m * IN_F + u * 8;
    float4v f0 = *(const float4v*)src;
    float4v f1 = *(const float4v*)(src + 4);
    short8 h;
#pragma unroll
    for (int j = 0; j < 4; ++j) {
        h[j]     = f2bf(f0[j]);
        h[j + 4] = f2bf(f1[j]);
    }
    *(short8*)(xbf2 + T * 8) = h;
}

// ---- pass 2: fused dequant + bf16 MFMA, dbuf LDS, async staging ----
__global__ __launch_bounds__(256, 2) void qlin_kernel(
    const short* __restrict__ xbf2,     // [512][64][8] bf16
    const int*   __restrict__ qweight,  // [512, 11008]
    const int*   __restrict__ qzeros,   // [32, 1376]
    const float* __restrict__ scales,   // [32, 11008]
    const float* __restrict__ bias,     // [11008]
    float* __restrict__ out)            // [64, 11008] pre-zeroed
{
    __shared__ short lds_a[2][16][64][8];   // 2 x 16 KB A-tiles, [u][m][8]

    const int blk  = blockIdx.x;
    const int nb   = blk % NBLK_N;
    const int kg   = blk / NBLK_N;
    const int t    = threadIdx.x;
    const int wave = t >> 6;
    const int lane = t & 63;
    const int q    = lane >> 4;
    const int nl   = lane & 15;
    const int n0   = nb * NT_BLK + wave * 32 + nl;
    const int n1   = n0 + 16;
    const int shz  = (n0 & 7) * 4;      // same for n1
    const int g0   = kg * GPB;

    float4v acc0[4], acc1[4];
#pragma unroll
    for (int i = 0; i < 4; ++i) {
        acc0[i] = (float4v){0.f, 0.f, 0.f, 0.f};
        acc1[i] = (float4v){0.f, 0.f, 0.f, 0.f};
    }

    // ---- staging: wave w DMAs u-rows [w*4, w*4+4) of group g into buf ----
#define STAGE(buf, g)                                                          \
    {                                                                          \
        _Pragma("unroll")                                                      \
        for (int i_ = 0; i_ < 4; ++i_) {                                       \
            const int u_ = wave * 4 + i_;                                      \
            const short* gsrc_ = xbf2 + (((g) * 16 + u_) * 64 + lane) * 8;     \
            __builtin_amdgcn_global_load_lds(                                  \
                (const __attribute__((address_space(1))) void*)gsrc_,          \
                (__attribute__((address_space(3))) void*)&lds_a[buf][u_][0][0],\
                16, 0, 0);                                                     \
        }                                                                      \
    }

#define LOAD_META(g, qw, zw0, zw1, s0v, s1v)                                   \
    {                                                                          \
        _Pragma("unroll")                                                      \
        for (int kk_ = 0; kk_ < 4; ++kk_) {                                    \
            const int row_ = (g) * 16 + kk_ * 4 + q;                           \
            qw[kk_]     = qweight[row_ * OUT_F + n0];                          \
            qw[kk_ + 4] = qweight[row_ * OUT_F + n1];                          \
        }                                                                      \
        zw0 = qzeros[(g) * QZ_WORDS + (n0 >> 3)];                              \
        zw1 = qzeros[(g) * QZ_WORDS + (n1 >> 3)];                              \
        s0v = scales[(g) * OUT_F + n0];                                        \
        s1v = scales[(g) * OUT_F + n1];                                        \
    }

    int qwc[8], zc0, zc1;
    float sc0, sc1;
    STAGE(0, g0);
    LOAD_META(g0, qwc, zc0, zc1, sc0, sc1);

#pragma unroll
    for (int gi = 0; gi < GPB; ++gi) {
        __syncthreads();   // vmcnt(0) drain: buf[gi&1] + current meta ready

        int qwn[8], zn0, zn1;
        float sn0, sn1;
        if (gi + 1 < GPB) {
            STAGE((gi + 1) & 1, g0 + gi + 1);             // DMA next tile
            LOAD_META(g0 + gi + 1, qwn, zn0, zn1, sn0, sn1);
        }

        const float s0  = sc0, s1 = sc1;
        const float nz0 = -s0 * (float)(((zc0 >> shz) & 15) + 1);
        const float nz1 = -s1 * (float)(((zc1 >> shz) & 15) + 1);

#pragma unroll
        for (int kk = 0; kk < 4; ++kk) {
            short8 b0, b1;
#pragma unroll
            for (int j = 0; j < 8; ++j) {
                b0[j] = f2bf_t(fmaf(s0, (float)((qwc[kk] >> (4 * j)) & 15), nz0));
                b1[j] = f2bf_t(fmaf(s1, (float)((qwc[kk + 4] >> (4 * j)) & 15), nz1));
            }
            const int u = kk * 4 + q;
#pragma unroll
            for (int mt = 0; mt < 4; ++mt) {
                short8 a = *(const short8*)&lds_a[gi & 1][u][mt * 16 + nl][0];
                acc0[mt] = __builtin_amdgcn_mfma_f32_16x16x32_bf16(a, b0, acc0[mt], 0, 0, 0);
                acc1[mt] = __builtin_amdgcn_mfma_f32_16x16x32_bf16(a, b1, acc1[mt], 0, 0, 0);
            }
        }

        if (gi + 1 < GPB) {
#pragma unroll
            for (int i = 0; i < 8; ++i) qwc[i] = qwn[i];
            zc0 = zn0; zc1 = zn1; sc0 = sn0; sc1 = sn1;
        }
    }

    // epilogue: C/D layout col = lane&15, row = q*4 + reg (proven R1/R3)
    const float bv0 = (kg == 0) ? bias[n0] : 0.f;
    const float bv1 = (kg == 0) ? bias[n1] : 0.f;
#pragma unroll
    for (int mt = 0; mt < 4; ++mt) {
#pragma unroll
        for (int r = 0; r < 4; ++r) {
            const int m = mt * 16 + q * 4 + r;
            atomicAdd(&out[m * OUT_F + n0], acc0[mt][r] + bv0);
            atomicAdd(&out[m * OUT_F + n1], acc1[mt][r] + bv1);
        }
    }
#undef STAGE
#undef LOAD_META
}

extern "C" void kernel_launch(void* const* d_in, const int* in_sizes, int n_in,
                              void* d_out, int out_size, void* d_ws, size_t ws_size,
                              hipStream_t stream) {
    const float* x       = (const float*)d_in[0];
    const int*   qweight = (const int*)d_in[1];
    const int*   qzeros  = (const int*)d_in[2];
    const float* scales  = (const float*)d_in[3];
    // d_in[4] = g_idx (structurally k/128; unused)
    const float* bias    = (const float*)d_in[5];
    float* out = (float*)d_out;
    short* xbf2 = (short*)d_ws;   // 512 KB of the 256 MB workspace

    hipMemsetAsync(out, 0, (size_t)M_ROWS * OUT_F * sizeof(float), stream);
    cvt_kernel<<<dim3((IN_F / 8) * M_ROWS / 256), dim3(256), 0, stream>>>(x, xbf2);
    qlin_kernel<<<dim3(NBLK_N * KSPLIT), dim3(256), 0, stream>>>(
        xbf2, qweight, qzeros, scales, bias, out);
}

// Round 5
// 95.403 us; speedup vs baseline: 1.2642x; 1.0738x over previous
//
#include <hip/hip_runtime.h>

#define IN_F 4096
#define OUT_F 11008
#define M_ROWS 64
#define KSPLIT 8
#define GPB 4                       // k-groups per block (32/KSPLIT)
#define NT_BLK 128                  // n-cols per block: 4 waves x 2 strips x 16
#define NBLK_N (OUT_F / NT_BLK)     // 86
#define QZ_WORDS (OUT_F / 8)        // 1376
#define SLICE (M_ROWS * OUT_F)      // 704512 floats per k-split partial

typedef __attribute__((ext_vector_type(8))) short short8;
typedef __attribute__((ext_vector_type(4))) float float4v;

// RNE fp32 -> bf16 (A-side, proven R1/R3/R4)
__device__ __forceinline__ short f2bf(float f) {
    unsigned u = __builtin_bit_cast(unsigned, f);
    return (short)((u + 0x7FFFu + ((u >> 16) & 1u)) >> 16);
}
// truncating fp32 -> bf16 (B-side, proven R3/R4)
__device__ __forceinline__ short f2bf_t(float f) {
    return (short)(__builtin_bit_cast(unsigned, f) >> 16);
}

// ---- pass 1: x [64,4096] fp32 -> xbf2 [512][64][8] bf16 (k-octet-major) ----
__global__ __launch_bounds__(256) void cvt_kernel(const float* __restrict__ x,
                                                  short* __restrict__ xbf2) {
    const int T = blockIdx.x * 256 + threadIdx.x;
    const int u = T >> 6, m = T & 63;
    const float* src = x + m * IN_F + u * 8;
    float4v f0 = *(const float4v*)src;
    float4v f1 = *(const float4v*)(src + 4);
    short8 h;
#pragma unroll
    for (int j = 0; j < 4; ++j) {
        h[j]     = f2bf(f0[j]);
        h[j + 4] = f2bf(f1[j]);
    }
    *(short8*)(xbf2 + T * 8) = h;
}

// ---- pass 2: fused dequant + bf16 MFMA, dbuf LDS, partial stores ----
__global__ __launch_bounds__(256, 2) void qlin_kernel(
    const short* __restrict__ xbf2,     // [512][64][8] bf16
    const int*   __restrict__ qweight,  // [512, 11008]
    const int*   __restrict__ qzeros,   // [32, 1376]
    const float* __restrict__ scales,   // [32, 11008]
    float* __restrict__ part)           // [KSPLIT][64][11008] partials
{
    __shared__ short lds_a[2][16][64][8];   // 2 x 16 KB A-tiles, [u][m][8]

    const int blk  = blockIdx.x;
    const int nb   = blk % NBLK_N;
    const int kg   = blk / NBLK_N;
    const int t    = threadIdx.x;
    const int wave = t >> 6;
    const int lane = t & 63;
    const int q    = lane >> 4;
    const int nl   = lane & 15;
    const int n0   = nb * NT_BLK + wave * 32 + nl;
    const int n1   = n0 + 16;
    const int shz  = (n0 & 7) * 4;      // same for n1
    const int g0   = kg * GPB;

    float4v acc0[4], acc1[4];
#pragma unroll
    for (int i = 0; i < 4; ++i) {
        acc0[i] = (float4v){0.f, 0.f, 0.f, 0.f};
        acc1[i] = (float4v){0.f, 0.f, 0.f, 0.f};
    }

#define STAGE(buf, g)                                                          \
    {                                                                          \
        _Pragma("unroll")                                                      \
        for (int i_ = 0; i_ < 4; ++i_) {                                       \
            const int u_ = wave * 4 + i_;                                      \
            const short* gsrc_ = xbf2 + (((g) * 16 + u_) * 64 + lane) * 8;     \
            __builtin_amdgcn_global_load_lds(                                  \
                (const __attribute__((address_space(1))) void*)gsrc_,          \
                (__attribute__((address_space(3))) void*)&lds_a[buf][u_][0][0],\
                16, 0, 0);                                                     \
        }                                                                      \
    }

#define LOAD_META(g, qw, zw0, zw1, s0v, s1v)                                   \
    {                                                                          \
        _Pragma("unroll")                                                      \
        for (int kk_ = 0; kk_ < 4; ++kk_) {                                    \
            const int row_ = (g) * 16 + kk_ * 4 + q;                           \
            qw[kk_]     = qweight[row_ * OUT_F + n0];                          \
            qw[kk_ + 4] = qweight[row_ * OUT_F + n1];                          \
        }                                                                      \
        zw0 = qzeros[(g) * QZ_WORDS + (n0 >> 3)];                              \
        zw1 = qzeros[(g) * QZ_WORDS + (n1 >> 3)];                              \
        s0v = scales[(g) * OUT_F + n0];                                        \
        s1v = scales[(g) * OUT_F + n1];                                        \
    }

    int qwc[8], zc0, zc1;
    float sc0, sc1;
    STAGE(0, g0);
    LOAD_META(g0, qwc, zc0, zc1, sc0, sc1);

#pragma unroll
    for (int gi = 0; gi < GPB; ++gi) {
        __syncthreads();   // buf[gi&1] + current meta ready

        int qwn[8], zn0, zn1;
        float sn0, sn1;
        if (gi + 1 < GPB) {
            STAGE((gi + 1) & 1, g0 + gi + 1);             // DMA next tile
            LOAD_META(g0 + gi + 1, qwn, zn0, zn1, sn0, sn1);
        }

        const float s0  = sc0, s1 = sc1;
        const float nz0 = -s0 * (float)(((zc0 >> shz) & 15) + 1);
        const float nz1 = -s1 * (float)(((zc1 >> shz) & 15) + 1);

#pragma unroll
        for (int kk = 0; kk < 4; ++kk) {
            short8 b0, b1;
#pragma unroll
            for (int j = 0; j < 8; ++j) {
                b0[j] = f2bf_t(fmaf(s0, (float)((qwc[kk] >> (4 * j)) & 15), nz0));
                b1[j] = f2bf_t(fmaf(s1, (float)((qwc[kk + 4] >> (4 * j)) & 15), nz1));
            }
            const int u = kk * 4 + q;
#pragma unroll
            for (int mt = 0; mt < 4; ++mt) {
                short8 a = *(const short8*)&lds_a[gi & 1][u][mt * 16 + nl][0];
                acc0[mt] = __builtin_amdgcn_mfma_f32_16x16x32_bf16(a, b0, acc0[mt], 0, 0, 0);
                acc1[mt] = __builtin_amdgcn_mfma_f32_16x16x32_bf16(a, b1, acc1[mt], 0, 0, 0);
            }
        }

        if (gi + 1 < GPB) {
#pragma unroll
            for (int i = 0; i < 8; ++i) qwc[i] = qwn[i];
            zc0 = zn0; zc1 = zn1; sc0 = sn0; sc1 = sn1;
        }
    }

    // epilogue: plain coalesced stores to this split's partial slice
    float* myp = part + kg * SLICE;
#pragma unroll
    for (int mt = 0; mt < 4; ++mt) {
#pragma unroll
        for (int r = 0; r < 4; ++r) {
            const int m = mt * 16 + q * 4 + r;
            myp[m * OUT_F + n0] = acc0[mt][r];
            myp[m * OUT_F + n1] = acc1[mt][r];
        }
    }
#undef STAGE
#undef LOAD_META
}

// ---- pass 3: sum KSPLIT partial slices + bias -> out ----
__global__ __launch_bounds__(256) void reduce_kernel(
    const float* __restrict__ part, const float* __restrict__ bias,
    float* __restrict__ out) {
    const int i4 = (blockIdx.x * 256 + threadIdx.x) * 4;
    const int n  = i4 % OUT_F;   // OUT_F % 4 == 0: float4 stays within a row
    float4v s = *(const float4v*)(bias + n);
#pragma unroll
    for (int kg = 0; kg < KSPLIT; ++kg)
        s += *(const float4v*)(part + kg * SLICE + i4);
    *(float4v*)(out + i4) = s;
}

extern "C" void kernel_launch(void* const* d_in, const int* in_sizes, int n_in,
                              void* d_out, int out_size, void* d_ws, size_t ws_size,
                              hipStream_t stream) {
    const float* x       = (const float*)d_in[0];
    const int*   qweight = (const int*)d_in[1];
    const int*   qzeros  = (const int*)d_in[2];
    const float* scales  = (const float*)d_in[3];
    // d_in[4] = g_idx (structurally k/128; unused)
    const float* bias    = (const float*)d_in[5];
    float* out = (float*)d_out;

    short* xbf2 = (short*)d_ws;                               // 512 KB
    float* part = (float*)((char*)d_ws + (1 << 20));          // 22.5 MB @ +1 MB

    cvt_kernel<<<dim3((IN_F / 8) * M_ROWS / 256), dim3(256), 0, stream>>>(x, xbf2);
    qlin_kernel<<<dim3(NBLK_N * KSPLIT), dim3(256), 0, stream>>>(
        xbf2, qweight, qzeros, scales, part);
    reduce_kernel<<<dim3(SLICE / 4 / 256), dim3(256), 0, stream>>>(part, bias, out);
}